// Round 8
// baseline (199.629 us; speedup 1.0000x reference)
//
#include <hip/hip_runtime.h>

#define TPB    256
#define VSHIFT 12
#define VBUCK  (1 << VSHIFT)        // 4096 vertices per bucket
#define NBMAX  256                  // max buckets (1e6/4096 = 245); == TPB
#define EPT    8                    // edges/thread/round, partition
#define ROUND  (TPB * EPT)          // 2048 edges/round
#define RPB    4                    // rounds per block
#define PBLK   (ROUND * RPB)        // 8192 edges/block

// Exclusive scan across TPB threads; also returns block total (uniform).
__device__ __forceinline__ int block_excl_scan(int v, int t, int* wsum, int* total) {
    int s = v;
    #pragma unroll
    for (int d = 1; d < 64; d <<= 1) {
        int u = __shfl_up(s, d);
        if ((t & 63) >= d) s += u;
    }
    if ((t & 63) == 63) wsum[t >> 6] = s;
    __syncthreads();
    int add = 0;
    #pragma unroll
    for (int w = 0; w < TPB / 64; ++w)
        if (w < (t >> 6)) add += wsum[w];
    int tot = wsum[0] + wsum[1] + wsum[2] + wsum[3];
    __syncthreads();                 // wsum safe for reuse
    *total = tot;
    return s + add - v;
}

// Per-partition-block bucket histogram, stored transposed: histp[b][blk].
__global__ void hist_blocks_kernel(const int* __restrict__ dst, long long n_edge,
                                   int nblk, int* __restrict__ histp) {
    __shared__ int h[NBMAX];
    const int t = threadIdx.x;
    h[t] = 0;
    __syncthreads();
    const long long bbase = (long long)blockIdx.x * PBLK;
    const long long bend0 = bbase + PBLK;
    const long long bend  = bend0 < n_edge ? bend0 : n_edge;
    #pragma unroll 4
    for (int j = 0; j < PBLK / TPB / 4; ++j) {
        long long e = bbase + ((long long)j * TPB + t) * 4;
        if (e + 4 <= bend) {
            int4 d = *reinterpret_cast<const int4*>(dst + e);
            atomicAdd(&h[d.x >> VSHIFT], 1);
            atomicAdd(&h[d.y >> VSHIFT], 1);
            atomicAdd(&h[d.z >> VSHIFT], 1);
            atomicAdd(&h[d.w >> VSHIFT], 1);
        } else {
            for (int q = 0; q < 4; ++q) {
                long long ee = e + q;
                if (ee < bend) atomicAdd(&h[dst[ee] >> VSHIFT], 1);
            }
        }
    }
    __syncthreads();
    histp[(size_t)t * nblk + blockIdx.x] = h[t];
}

// One block per bucket: exclusive-scan its row of per-block counts in place;
// write the bucket total.
__global__ void row_scan_kernel(int* __restrict__ histp, int nblk,
                                int* __restrict__ totals) {
    __shared__ int wsum[TPB / 64];
    const int t = threadIdx.x;
    int* row = histp + (size_t)blockIdx.x * nblk;
    int carry = 0;
    for (int base = 0; base < nblk; base += TPB) {
        int v = (base + t < nblk) ? row[base + t] : 0;
        int tot;
        int excl = block_excl_scan(v, t, wsum, &tot);
        if (base + t < nblk) row[base + t] = carry + excl;
        carry += tot;
        __syncthreads();
    }
    if (t == 0) totals[blockIdx.x] = carry;
}

// Exclusive scan of bucket totals -> bucket base offsets (base[NBMAX+1]).
__global__ void base_scan_kernel(const int* __restrict__ totals, int nb,
                                 int* __restrict__ base) {
    __shared__ int wsum[TPB / 64];
    const int t = threadIdx.x;
    int v = (t < nb) ? totals[t] : 0;
    int tot;
    int excl = block_excl_scan(v, t, wsum, &tot);
    base[t] = excl;
    if (t == TPB - 1) base[TPB] = excl + v;
}

// Partition edges into per-bucket regions (u16 local idx + f32 val, 6 B/edge).
// Offsets fully precomputed: no global cursor atomics. LDS-staged sorted flush.
__global__ __launch_bounds__(TPB, 7)
void partition_kernel(const int* __restrict__ dst,
                      const float* __restrict__ ea,
                      long long n_edge, int nblk,
                      const int* __restrict__ histp,
                      const int* __restrict__ base,
                      unsigned short* __restrict__ gidx,
                      float* __restrict__ gval) {
    __shared__ unsigned int stage_d[ROUND];   // 8 KB: full dst, bucket-sorted
    __shared__ float        stage_v[ROUND];   // 8 KB
    __shared__ int h[NBMAX];      // round histogram
    __shared__ int pos[NBMAX];    // round scatter cursors
    __shared__ int adj[NBMAX];    // gbase - pfx per bucket
    __shared__ int gbase[NBMAX];  // running global offset per bucket
    __shared__ int wsum[TPB / 64];

    const int t   = threadIdx.x;
    const int blk = blockIdx.x;
    const long long bbase = (long long)blk * PBLK;
    const long long bend0 = bbase + PBLK;
    const long long bend  = bend0 < n_edge ? bend0 : n_edge;

    gbase[t] = base[t] + histp[(size_t)t * nblk + blk];

    for (int r = 0; r < RPB; ++r) {
        const long long rbase = bbase + (long long)r * ROUND;
        if (rbase >= bend) break;              // uniform across block
        h[t] = 0;
        __syncthreads();

        // Load round's edges into registers + round histogram.
        int4   dreg[EPT / 4];
        float4 vreg[EPT / 4];
        int    nval[EPT / 4];
        #pragma unroll
        for (int j = 0; j < EPT / 4; ++j) {
            long long e = rbase + ((long long)j * TPB + t) * 4;
            if (e + 4 <= bend) {
                dreg[j] = *reinterpret_cast<const int4*>(dst + e);
                vreg[j] = *reinterpret_cast<const float4*>(ea + e);
                nval[j] = 4;
            } else {
                int dd[4] = {0, 0, 0, 0};
                float vv[4] = {0.f, 0.f, 0.f, 0.f};
                int nv = 0;
                for (int q = 0; q < 4; ++q) {
                    long long ee = e + q;
                    if (ee < bend) { dd[q] = dst[ee]; vv[q] = ea[ee]; nv = q + 1; }
                }
                dreg[j] = make_int4(dd[0], dd[1], dd[2], dd[3]);
                vreg[j] = make_float4(vv[0], vv[1], vv[2], vv[3]);
                nval[j] = nv;
            }
            if (nval[j] > 0) atomicAdd(&h[dreg[j].x >> VSHIFT], 1);
            if (nval[j] > 1) atomicAdd(&h[dreg[j].y >> VSHIFT], 1);
            if (nval[j] > 2) atomicAdd(&h[dreg[j].z >> VSHIFT], 1);
            if (nval[j] > 3) atomicAdd(&h[dreg[j].w >> VSHIFT], 1);
        }
        __syncthreads();

        int rt;
        int excl = block_excl_scan(h[t], t, wsum, &rt);
        pos[t] = excl;
        adj[t] = gbase[t] - excl;
        __syncthreads();

        // Scatter into bucket-sorted LDS staging.
        #pragma unroll
        for (int j = 0; j < EPT / 4; ++j) {
            int   dd[4] = {dreg[j].x, dreg[j].y, dreg[j].z, dreg[j].w};
            float vv[4] = {vreg[j].x, vreg[j].y, vreg[j].z, vreg[j].w};
            #pragma unroll
            for (int q = 0; q < 4; ++q) {
                if (q < nval[j]) {
                    int b = dd[q] >> VSHIFT;
                    int slot = atomicAdd(&pos[b], 1);
                    stage_d[slot] = (unsigned)dd[q];
                    stage_v[slot] = vv[q];
                }
            }
        }
        __syncthreads();

        // Coalesced flush: consecutive slots -> consecutive global addresses.
        for (int i = t; i < rt; i += TPB) {
            unsigned d = stage_d[i];
            int b = (int)(d >> VSHIFT);
            int gi = adj[b] + i;
            gidx[gi] = (unsigned short)(d & (VBUCK - 1));
            gval[gi] = stage_v[i];
        }
        __syncthreads();
        gbase[t] += h[t];
    }
}

// One block per bucket: accumulate into LDS, then fused vertex update.
__global__ void accum_update_kernel(const unsigned short* __restrict__ gidx,
                                    const float* __restrict__ gval,
                                    const int* __restrict__ base,
                                    const float* __restrict__ va,
                                    const float* __restrict__ g,
                                    float* __restrict__ out, int n_vert) {
    __shared__ __align__(16) float acc[VBUCK];
    const int b = blockIdx.x;
    const int T = blockDim.x;                  // 1024
    for (int t = threadIdx.x; t < VBUCK; t += T) acc[t] = 0.f;
    __syncthreads();
    const int s = base[b];
    const int e = base[b + 1];
    for (int i = s + threadIdx.x; i < e; i += T) {
        atomicAdd(&acc[gidx[i]], gval[i]);
    }
    __syncthreads();

    const float w = g[0];
    const int vbase = b << VSHIFT;
    const int t = threadIdx.x;
    const int v0 = vbase + t * 4;
    if (v0 + 4 <= n_vert) {
        const int gt = v0 >> 2;
        float4 f0 = reinterpret_cast<const float4*>(va)[gt * 3 + 0];
        float4 f1 = reinterpret_cast<const float4*>(va)[gt * 3 + 1];
        float4 f2 = reinterpret_cast<const float4*>(va)[gt * 3 + 2];
        float4 c  = reinterpret_cast<const float4*>(acc)[t];
        float4 o0, o1, o2;
        o0.x = f0.x; o0.y = f0.y; o0.z = f0.z + w * (f0.y - c.x) / f0.x;
        o0.w = f0.w; o1.x = f1.x; o1.y = f1.y + w * (f1.x - c.y) / f0.w;
        o1.z = f1.z; o1.w = f1.w; o2.x = f2.x + w * (f1.w - c.z) / f1.z;
        o2.y = f2.y; o2.z = f2.z; o2.w = f2.w + w * (f2.z - c.w) / f2.y;
        reinterpret_cast<float4*>(out)[gt * 3 + 0] = o0;
        reinterpret_cast<float4*>(out)[gt * 3 + 1] = o1;
        reinterpret_cast<float4*>(out)[gt * 3 + 2] = o2;
    } else {
        for (int i = v0; i < n_vert && i < v0 + 4; ++i) {
            float A = va[3 * i], bb = va[3 * i + 1], x = va[3 * i + 2];
            out[3 * i]     = A;
            out[3 * i + 1] = bb;
            out[3 * i + 2] = x + w * (bb - acc[i - vbase]) / A;
        }
    }
}

// ---- fallback path (insufficient scratch): device-scope atomics ----
__global__ void scatter_add_dev_kernel(const int* __restrict__ dst,
                                       const float* __restrict__ ea,
                                       float* __restrict__ acc, int n_edges4) {
    int i = blockIdx.x * blockDim.x + threadIdx.x;
    const int stride = gridDim.x * blockDim.x;
    for (; i < n_edges4; i += stride) {
        int4   d = reinterpret_cast<const int4*>(dst)[i];
        float4 v = reinterpret_cast<const float4*>(ea)[i];
        atomicAdd(&acc[d.x], v.x);
        atomicAdd(&acc[d.y], v.y);
        atomicAdd(&acc[d.z], v.z);
        atomicAdd(&acc[d.w], v.w);
    }
}

__global__ void update_kernel(const float* __restrict__ va,
                              const float* __restrict__ cbar,
                              const float* __restrict__ g,
                              float* __restrict__ out, int n) {
    int i = blockIdx.x * blockDim.x + threadIdx.x;
    if (i >= n) return;
    float A = va[3 * i], b = va[3 * i + 1], x = va[3 * i + 2];
    out[3 * i]     = A;
    out[3 * i + 1] = b;
    out[3 * i + 2] = x + g[0] * (b - cbar[i]) / A;
}

extern "C" void kernel_launch(void* const* d_in, const int* in_sizes, int n_in,
                              void* d_out, int out_size, void* d_ws, size_t ws_size,
                              hipStream_t stream) {
    const float* vertex_attr = (const float*)d_in[0];
    const int*   edgeij      = (const int*)d_in[1];   // row 0 = dst
    const float* edge_attr   = (const float*)d_in[2];
    const float* g           = (const float*)d_in[3];

    const int       n_vert = in_sizes[0] / 3;
    const long long n_edge = in_sizes[2];
    const int       nb     = (n_vert + VBUCK - 1) >> VSHIFT;
    const int       nblk   = (int)((n_edge + PBLK - 1) / PBLK);

    // ws layout: [histp: NBMAX*nblk][totals][base][gidx: n_edge u16][gval: n_edge f32]
    size_t histp_sz   = (size_t)NBMAX * nblk * sizeof(int);
    size_t totals_off = (histp_sz + 255) & ~(size_t)255;
    size_t base_off   = totals_off + NBMAX * sizeof(int);
    size_t gidx_off   = (base_off + (TPB + 1) * sizeof(int) + 255) & ~(size_t)255;
    size_t gval_off   = (gidx_off + (size_t)n_edge * sizeof(unsigned short) + 255)
                        & ~(size_t)255;
    size_t need       = gval_off + (size_t)n_edge * sizeof(float);

    if (ws_size >= need && nb <= NBMAX) {
        int* histp  = (int*)d_ws;
        int* totals = (int*)((char*)d_ws + totals_off);
        int* basep  = (int*)((char*)d_ws + base_off);
        unsigned short* gidx = (unsigned short*)((char*)d_ws + gidx_off);
        float*          gval = (float*)((char*)d_ws + gval_off);

        hist_blocks_kernel<<<nblk, TPB, 0, stream>>>(edgeij, n_edge, nblk, histp);
        row_scan_kernel<<<nb, TPB, 0, stream>>>(histp, nblk, totals);
        base_scan_kernel<<<1, TPB, 0, stream>>>(totals, nb, basep);
        partition_kernel<<<nblk, TPB, 0, stream>>>(edgeij, edge_attr, n_edge,
                                                   nblk, histp, basep, gidx, gval);
        accum_update_kernel<<<nb, 1024, 0, stream>>>(gidx, gval, basep,
                                                     vertex_attr, g,
                                                     (float*)d_out, n_vert);
    } else {
        float* cbar = (float*)d_ws;
        hipMemsetAsync(cbar, 0, (size_t)n_vert * sizeof(float), stream);
        scatter_add_dev_kernel<<<4096, TPB, 0, stream>>>(edgeij, edge_attr, cbar,
                                                         (int)(n_edge / 4));
        update_kernel<<<(n_vert + TPB - 1) / TPB, TPB, 0, stream>>>(
            vertex_attr, cbar, g, (float*)d_out, n_vert);
    }
}

// Round 9
// 174.327 us; speedup vs baseline: 1.1451x; 1.1451x over previous
//
#include <hip/hip_runtime.h>

#define TPB    256
#define VSHIFT 12
#define VBUCK  (1 << VSHIFT)        // 4096 vertices per bucket
#define NBMAX  256                  // max buckets (1e6/4096 = 245); == TPB
#define EPT    16                   // edges/thread/round, partition
#define ROUND  (TPB * EPT)          // 4096 edges/round
#define RPB    4                    // rounds per block
#define PBLK   (ROUND * RPB)        // 16384 edges/block

__device__ __forceinline__ unsigned long long pack_pair(int d, float v) {
    return (unsigned long long)(unsigned)d |
           ((unsigned long long)__float_as_uint(v) << 32);
}

// Exclusive scan across TPB threads; also returns block total (uniform).
__device__ __forceinline__ int block_excl_scan(int v, int t, int* wsum, int* total) {
    int s = v;
    #pragma unroll
    for (int d = 1; d < 64; d <<= 1) {
        int u = __shfl_up(s, d);
        if ((t & 63) >= d) s += u;
    }
    if ((t & 63) == 63) wsum[t >> 6] = s;
    __syncthreads();
    int add = 0;
    #pragma unroll
    for (int w = 0; w < TPB / 64; ++w)
        if (w < (t >> 6)) add += wsum[w];
    int tot = wsum[0] + wsum[1] + wsum[2] + wsum[3];
    __syncthreads();                 // wsum safe for reuse
    *total = tot;
    return s + add - v;
}

// Per-partition-block bucket histogram, stored transposed: histp[b][blk].
__global__ void hist_blocks_kernel(const int* __restrict__ dst, long long n_edge,
                                   int nblk, int* __restrict__ histp) {
    __shared__ int h[NBMAX];
    const int t = threadIdx.x;
    h[t] = 0;
    __syncthreads();
    const long long bbase = (long long)blockIdx.x * PBLK;
    const long long bend0 = bbase + PBLK;
    const long long bend  = bend0 < n_edge ? bend0 : n_edge;
    #pragma unroll 4
    for (int j = 0; j < PBLK / TPB / 4; ++j) {
        long long e = bbase + ((long long)j * TPB + t) * 4;
        if (e + 4 <= bend) {
            int4 d = *reinterpret_cast<const int4*>(dst + e);
            atomicAdd(&h[d.x >> VSHIFT], 1);
            atomicAdd(&h[d.y >> VSHIFT], 1);
            atomicAdd(&h[d.z >> VSHIFT], 1);
            atomicAdd(&h[d.w >> VSHIFT], 1);
        } else {
            for (int q = 0; q < 4; ++q) {
                long long ee = e + q;
                if (ee < bend) atomicAdd(&h[dst[ee] >> VSHIFT], 1);
            }
        }
    }
    __syncthreads();
    histp[(size_t)t * nblk + blockIdx.x] = h[t];
}

// One block per bucket: exclusive-scan its row of per-block counts in place;
// write the bucket total.
__global__ void row_scan_kernel(int* __restrict__ histp, int nblk,
                                int* __restrict__ totals) {
    __shared__ int wsum[TPB / 64];
    const int t = threadIdx.x;
    int* row = histp + (size_t)blockIdx.x * nblk;
    int carry = 0;
    for (int base = 0; base < nblk; base += TPB) {
        int v = (base + t < nblk) ? row[base + t] : 0;
        int tot;
        int excl = block_excl_scan(v, t, wsum, &tot);
        if (base + t < nblk) row[base + t] = carry + excl;
        carry += tot;
        __syncthreads();
    }
    if (t == 0) totals[blockIdx.x] = carry;
}

// Exclusive scan of bucket totals -> bucket base offsets (base[NBMAX+1]).
__global__ void base_scan_kernel(const int* __restrict__ totals, int nb,
                                 int* __restrict__ base) {
    __shared__ int wsum[TPB / 64];
    const int t = threadIdx.x;
    int v = (t < nb) ? totals[t] : 0;
    int tot;
    int excl = block_excl_scan(v, t, wsum, &tot);
    base[t] = excl;
    if (t == TPB - 1) base[TPB] = excl + v;
}

// Partition edges into per-bucket pair regions. Offsets fully precomputed.
// Fast path (full blocks): double-buffered register prefetch so next round's
// HBM loads are in flight during this round's LDS phases + flush.
__global__ __launch_bounds__(TPB, 4)
void partition_kernel(const int* __restrict__ dst,
                      const float* __restrict__ ea,
                      long long n_edge, int nblk,
                      const int* __restrict__ histp,
                      const int* __restrict__ base,
                      unsigned long long* __restrict__ pairs) {
    __shared__ unsigned long long stage[ROUND];   // 32 KB, bucket-sorted pairs
    __shared__ int h[NBMAX];      // round histogram
    __shared__ int pos[NBMAX];    // round scatter cursors
    __shared__ int adj[NBMAX];    // gbase - pfx per bucket
    __shared__ int wsum[TPB / 64];

    const int t = threadIdx.x;
    const long long bbase = (long long)blockIdx.x * PBLK;
    int my_gbase = base[t] + histp[(size_t)t * nblk + blockIdx.x];

    if (bbase + PBLK <= n_edge) {
        // ---------- fast path: full block, prefetch double-buffer ----------
        int4   dr[2][EPT / 4];
        float4 vr[2][EPT / 4];
        #pragma unroll
        for (int j = 0; j < EPT / 4; ++j) {
            long long e = bbase + ((long long)j * TPB + t) * 4;
            dr[0][j] = *reinterpret_cast<const int4*>(dst + e);
            vr[0][j] = *reinterpret_cast<const float4*>(ea + e);
        }
        #pragma unroll
        for (int r = 0; r < RPB; ++r) {
            const int cur = r & 1, nxt = cur ^ 1;
            if (r + 1 < RPB) {                    // issue next round's loads NOW
                const long long pb = bbase + (long long)(r + 1) * ROUND;
                #pragma unroll
                for (int j = 0; j < EPT / 4; ++j) {
                    long long e = pb + ((long long)j * TPB + t) * 4;
                    dr[nxt][j] = *reinterpret_cast<const int4*>(dst + e);
                    vr[nxt][j] = *reinterpret_cast<const float4*>(ea + e);
                }
            }
            h[t] = 0;
            __syncthreads();
            #pragma unroll
            for (int j = 0; j < EPT / 4; ++j) {
                atomicAdd(&h[dr[cur][j].x >> VSHIFT], 1);
                atomicAdd(&h[dr[cur][j].y >> VSHIFT], 1);
                atomicAdd(&h[dr[cur][j].z >> VSHIFT], 1);
                atomicAdd(&h[dr[cur][j].w >> VSHIFT], 1);
            }
            __syncthreads();
            int rt;
            int excl = block_excl_scan(h[t], t, wsum, &rt);
            pos[t] = excl;
            adj[t] = my_gbase - excl;
            __syncthreads();
            #pragma unroll
            for (int j = 0; j < EPT / 4; ++j) {
                int   dd[4] = {dr[cur][j].x, dr[cur][j].y, dr[cur][j].z, dr[cur][j].w};
                float vv[4] = {vr[cur][j].x, vr[cur][j].y, vr[cur][j].z, vr[cur][j].w};
                #pragma unroll
                for (int q = 0; q < 4; ++q) {
                    int b = dd[q] >> VSHIFT;
                    int slot = atomicAdd(&pos[b], 1);
                    stage[slot] = pack_pair(dd[q], vv[q]);
                }
            }
            __syncthreads();
            #pragma unroll
            for (int i0 = 0; i0 < ROUND; i0 += TPB) {   // rt == ROUND here
                int i = i0 + t;
                unsigned long long p = stage[i];
                int b = (int)((unsigned)(p & 0xffffffffull) >> VSHIFT);
                pairs[(size_t)(adj[b] + i)] = p;
            }
            my_gbase += h[t];
            // no trailing barrier: next round's post-reset barrier protects
            // stage (rewritten only after 3 barriers) and adj (after 2).
        }
    } else {
        // ---------- guarded tail path (last block only) ----------
        const long long bend = n_edge;
        for (int r = 0; r < RPB; ++r) {
            const long long rbase = bbase + (long long)r * ROUND;
            if (rbase >= bend) break;              // uniform across block
            h[t] = 0;
            __syncthreads();

            int4   dreg[EPT / 4];
            float4 vreg[EPT / 4];
            int    nval[EPT / 4];
            #pragma unroll
            for (int j = 0; j < EPT / 4; ++j) {
                long long e = rbase + ((long long)j * TPB + t) * 4;
                if (e + 4 <= bend) {
                    dreg[j] = *reinterpret_cast<const int4*>(dst + e);
                    vreg[j] = *reinterpret_cast<const float4*>(ea + e);
                    nval[j] = 4;
                } else {
                    int dd[4] = {0, 0, 0, 0};
                    float vv[4] = {0.f, 0.f, 0.f, 0.f};
                    int nv = 0;
                    for (int q = 0; q < 4; ++q) {
                        long long ee = e + q;
                        if (ee < bend) { dd[q] = dst[ee]; vv[q] = ea[ee]; nv = q + 1; }
                    }
                    dreg[j] = make_int4(dd[0], dd[1], dd[2], dd[3]);
                    vreg[j] = make_float4(vv[0], vv[1], vv[2], vv[3]);
                    nval[j] = nv;
                }
                if (nval[j] > 0) atomicAdd(&h[dreg[j].x >> VSHIFT], 1);
                if (nval[j] > 1) atomicAdd(&h[dreg[j].y >> VSHIFT], 1);
                if (nval[j] > 2) atomicAdd(&h[dreg[j].z >> VSHIFT], 1);
                if (nval[j] > 3) atomicAdd(&h[dreg[j].w >> VSHIFT], 1);
            }
            __syncthreads();

            int rt;
            int excl = block_excl_scan(h[t], t, wsum, &rt);
            pos[t] = excl;
            adj[t] = my_gbase - excl;
            __syncthreads();

            #pragma unroll
            for (int j = 0; j < EPT / 4; ++j) {
                int   dd[4] = {dreg[j].x, dreg[j].y, dreg[j].z, dreg[j].w};
                float vv[4] = {vreg[j].x, vreg[j].y, vreg[j].z, vreg[j].w};
                #pragma unroll
                for (int q = 0; q < 4; ++q) {
                    if (q < nval[j]) {
                        int b = dd[q] >> VSHIFT;
                        int slot = atomicAdd(&pos[b], 1);
                        stage[slot] = pack_pair(dd[q], vv[q]);
                    }
                }
            }
            __syncthreads();

            for (int i = t; i < rt; i += TPB) {
                unsigned long long p = stage[i];
                int b = (int)((unsigned)(p & 0xffffffffull) >> VSHIFT);
                pairs[(size_t)(adj[b] + i)] = p;
            }
            __syncthreads();
            my_gbase += h[t];
        }
    }
}

// One block per bucket: accumulate pairs into LDS, then fused vertex update.
__global__ void accum_update_kernel(const unsigned long long* __restrict__ pairs,
                                    const int* __restrict__ base,
                                    const float* __restrict__ va,
                                    const float* __restrict__ g,
                                    float* __restrict__ out, int n_vert) {
    __shared__ __align__(16) float acc[VBUCK];
    const int b = blockIdx.x;
    const int T = blockDim.x;                  // 1024
    for (int t = threadIdx.x; t < VBUCK; t += T) acc[t] = 0.f;
    __syncthreads();
    const int s = base[b];
    const int e = base[b + 1];
    for (int i = s + threadIdx.x; i < e; i += T) {
        unsigned long long p = pairs[i];
        atomicAdd(&acc[(int)(p & (VBUCK - 1))],
                  __uint_as_float((unsigned)(p >> 32)));
    }
    __syncthreads();

    const float w = g[0];
    const int vbase = b << VSHIFT;
    const int t = threadIdx.x;
    const int v0 = vbase + t * 4;
    if (v0 + 4 <= n_vert) {
        const int gt = v0 >> 2;
        float4 f0 = reinterpret_cast<const float4*>(va)[gt * 3 + 0];
        float4 f1 = reinterpret_cast<const float4*>(va)[gt * 3 + 1];
        float4 f2 = reinterpret_cast<const float4*>(va)[gt * 3 + 2];
        float4 c  = reinterpret_cast<const float4*>(acc)[t];
        float4 o0, o1, o2;
        o0.x = f0.x; o0.y = f0.y; o0.z = f0.z + w * (f0.y - c.x) / f0.x;
        o0.w = f0.w; o1.x = f1.x; o1.y = f1.y + w * (f1.x - c.y) / f0.w;
        o1.z = f1.z; o1.w = f1.w; o2.x = f2.x + w * (f1.w - c.z) / f1.z;
        o2.y = f2.y; o2.z = f2.z; o2.w = f2.w + w * (f2.z - c.w) / f2.y;
        reinterpret_cast<float4*>(out)[gt * 3 + 0] = o0;
        reinterpret_cast<float4*>(out)[gt * 3 + 1] = o1;
        reinterpret_cast<float4*>(out)[gt * 3 + 2] = o2;
    } else {
        for (int i = v0; i < n_vert && i < v0 + 4; ++i) {
            float A = va[3 * i], bb = va[3 * i + 1], x = va[3 * i + 2];
            out[3 * i]     = A;
            out[3 * i + 1] = bb;
            out[3 * i + 2] = x + w * (bb - acc[i - vbase]) / A;
        }
    }
}

// ---- fallback path (insufficient scratch): device-scope atomics ----
__global__ void scatter_add_dev_kernel(const int* __restrict__ dst,
                                       const float* __restrict__ ea,
                                       float* __restrict__ acc, int n_edges4) {
    int i = blockIdx.x * blockDim.x + threadIdx.x;
    const int stride = gridDim.x * blockDim.x;
    for (; i < n_edges4; i += stride) {
        int4   d = reinterpret_cast<const int4*>(dst)[i];
        float4 v = reinterpret_cast<const float4*>(ea)[i];
        atomicAdd(&acc[d.x], v.x);
        atomicAdd(&acc[d.y], v.y);
        atomicAdd(&acc[d.z], v.z);
        atomicAdd(&acc[d.w], v.w);
    }
}

__global__ void update_kernel(const float* __restrict__ va,
                              const float* __restrict__ cbar,
                              const float* __restrict__ g,
                              float* __restrict__ out, int n) {
    int i = blockIdx.x * blockDim.x + threadIdx.x;
    if (i >= n) return;
    float A = va[3 * i], b = va[3 * i + 1], x = va[3 * i + 2];
    out[3 * i]     = A;
    out[3 * i + 1] = b;
    out[3 * i + 2] = x + g[0] * (b - cbar[i]) / A;
}

extern "C" void kernel_launch(void* const* d_in, const int* in_sizes, int n_in,
                              void* d_out, int out_size, void* d_ws, size_t ws_size,
                              hipStream_t stream) {
    const float* vertex_attr = (const float*)d_in[0];
    const int*   edgeij      = (const int*)d_in[1];   // row 0 = dst
    const float* edge_attr   = (const float*)d_in[2];
    const float* g           = (const float*)d_in[3];

    const int       n_vert = in_sizes[0] / 3;
    const long long n_edge = in_sizes[2];
    const int       nb     = (n_vert + VBUCK - 1) >> VSHIFT;
    const int       nblk   = (int)((n_edge + PBLK - 1) / PBLK);

    // ws layout: [histp: NBMAX*nblk][totals: NBMAX][base: TPB+1][pairs: n_edge]
    size_t histp_sz   = (size_t)NBMAX * nblk * sizeof(int);
    size_t totals_off = (histp_sz + 255) & ~(size_t)255;
    size_t base_off   = totals_off + NBMAX * sizeof(int);
    size_t pairs_off  = (base_off + (TPB + 1) * sizeof(int) + 255) & ~(size_t)255;
    size_t need       = pairs_off + (size_t)n_edge * sizeof(unsigned long long);

    if (ws_size >= need && nb <= NBMAX) {
        int* histp  = (int*)d_ws;
        int* totals = (int*)((char*)d_ws + totals_off);
        int* basep  = (int*)((char*)d_ws + base_off);
        unsigned long long* pairs =
            (unsigned long long*)((char*)d_ws + pairs_off);

        hist_blocks_kernel<<<nblk, TPB, 0, stream>>>(edgeij, n_edge, nblk, histp);
        row_scan_kernel<<<nb, TPB, 0, stream>>>(histp, nblk, totals);
        base_scan_kernel<<<1, TPB, 0, stream>>>(totals, nb, basep);
        partition_kernel<<<nblk, TPB, 0, stream>>>(edgeij, edge_attr, n_edge,
                                                   nblk, histp, basep, pairs);
        accum_update_kernel<<<nb, 1024, 0, stream>>>(pairs, basep, vertex_attr,
                                                     g, (float*)d_out, n_vert);
    } else {
        float* cbar = (float*)d_ws;
        hipMemsetAsync(cbar, 0, (size_t)n_vert * sizeof(float), stream);
        scatter_add_dev_kernel<<<4096, TPB, 0, stream>>>(edgeij, edge_attr, cbar,
                                                         (int)(n_edge / 4));
        update_kernel<<<(n_vert + TPB - 1) / TPB, TPB, 0, stream>>>(
            vertex_attr, cbar, g, (float*)d_out, n_vert);
    }
}

// Round 10
// 173.512 us; speedup vs baseline: 1.1505x; 1.0047x over previous
//
#include <hip/hip_runtime.h>

#define TPB    256
#define VSHIFT 12
#define VBUCK  (1 << VSHIFT)        // 4096 vertices per bucket
#define NBMAX  256                  // max buckets (1e6/4096 = 245); == TPB
#define EPT    16                   // edges/thread/round, partition
#define ROUND  (TPB * EPT)          // 4096 edges/round
#define RPB    4                    // rounds per block
#define PBLK   (ROUND * RPB)        // 16384 edges/block
#define SPLIT  2                    // accumulate sub-blocks per bucket
#define ATPB   1024                 // accumulate threads per block

__device__ __forceinline__ unsigned long long pack_pair(int d, float v) {
    return (unsigned long long)(unsigned)d |
           ((unsigned long long)__float_as_uint(v) << 32);
}

// Exclusive scan across TPB threads; also returns block total (uniform).
__device__ __forceinline__ int block_excl_scan(int v, int t, int* wsum, int* total) {
    int s = v;
    #pragma unroll
    for (int d = 1; d < 64; d <<= 1) {
        int u = __shfl_up(s, d);
        if ((t & 63) >= d) s += u;
    }
    if ((t & 63) == 63) wsum[t >> 6] = s;
    __syncthreads();
    int add = 0;
    #pragma unroll
    for (int w = 0; w < TPB / 64; ++w)
        if (w < (t >> 6)) add += wsum[w];
    int tot = wsum[0] + wsum[1] + wsum[2] + wsum[3];
    __syncthreads();                 // wsum safe for reuse
    *total = tot;
    return s + add - v;
}

// Per-partition-block bucket histogram, stored transposed: histp[b][blk].
__global__ void hist_blocks_kernel(const int* __restrict__ dst, long long n_edge,
                                   int nblk, int* __restrict__ histp) {
    __shared__ int h[NBMAX];
    const int t = threadIdx.x;
    h[t] = 0;
    __syncthreads();
    const long long bbase = (long long)blockIdx.x * PBLK;
    const long long bend0 = bbase + PBLK;
    const long long bend  = bend0 < n_edge ? bend0 : n_edge;
    #pragma unroll 4
    for (int j = 0; j < PBLK / TPB / 4; ++j) {
        long long e = bbase + ((long long)j * TPB + t) * 4;
        if (e + 4 <= bend) {
            int4 d = *reinterpret_cast<const int4*>(dst + e);
            atomicAdd(&h[d.x >> VSHIFT], 1);
            atomicAdd(&h[d.y >> VSHIFT], 1);
            atomicAdd(&h[d.z >> VSHIFT], 1);
            atomicAdd(&h[d.w >> VSHIFT], 1);
        } else {
            for (int q = 0; q < 4; ++q) {
                long long ee = e + q;
                if (ee < bend) atomicAdd(&h[dst[ee] >> VSHIFT], 1);
            }
        }
    }
    __syncthreads();
    histp[(size_t)t * nblk + blockIdx.x] = h[t];
}

// One block per bucket: exclusive-scan its row of per-block counts in place;
// write the bucket total.
__global__ void row_scan_kernel(int* __restrict__ histp, int nblk,
                                int* __restrict__ totals) {
    __shared__ int wsum[TPB / 64];
    const int t = threadIdx.x;
    int* row = histp + (size_t)blockIdx.x * nblk;
    int carry = 0;
    for (int base = 0; base < nblk; base += TPB) {
        int v = (base + t < nblk) ? row[base + t] : 0;
        int tot;
        int excl = block_excl_scan(v, t, wsum, &tot);
        if (base + t < nblk) row[base + t] = carry + excl;
        carry += tot;
        __syncthreads();
    }
    if (t == 0) totals[blockIdx.x] = carry;
}

// Exclusive scan of bucket totals -> bucket base offsets (base[NBMAX+1]).
__global__ void base_scan_kernel(const int* __restrict__ totals, int nb,
                                 int* __restrict__ base) {
    __shared__ int wsum[TPB / 64];
    const int t = threadIdx.x;
    int v = (t < nb) ? totals[t] : 0;
    int tot;
    int excl = block_excl_scan(v, t, wsum, &tot);
    base[t] = excl;
    if (t == TPB - 1) base[TPB] = excl + v;
}

// Partition edges into per-bucket pair regions. Offsets fully precomputed.
// Fast path (full blocks): double-buffered register prefetch so next round's
// HBM loads are in flight during this round's LDS phases + flush.
__global__ __launch_bounds__(TPB, 4)
void partition_kernel(const int* __restrict__ dst,
                      const float* __restrict__ ea,
                      long long n_edge, int nblk,
                      const int* __restrict__ histp,
                      const int* __restrict__ base,
                      unsigned long long* __restrict__ pairs) {
    __shared__ unsigned long long stage[ROUND];   // 32 KB, bucket-sorted pairs
    __shared__ int h[NBMAX];      // round histogram
    __shared__ int pos[NBMAX];    // round scatter cursors
    __shared__ int adj[NBMAX];    // gbase - pfx per bucket
    __shared__ int wsum[TPB / 64];

    const int t = threadIdx.x;
    const long long bbase = (long long)blockIdx.x * PBLK;
    int my_gbase = base[t] + histp[(size_t)t * nblk + blockIdx.x];

    if (bbase + PBLK <= n_edge) {
        // ---------- fast path: full block, prefetch double-buffer ----------
        int4   dr[2][EPT / 4];
        float4 vr[2][EPT / 4];
        #pragma unroll
        for (int j = 0; j < EPT / 4; ++j) {
            long long e = bbase + ((long long)j * TPB + t) * 4;
            dr[0][j] = *reinterpret_cast<const int4*>(dst + e);
            vr[0][j] = *reinterpret_cast<const float4*>(ea + e);
        }
        #pragma unroll
        for (int r = 0; r < RPB; ++r) {
            const int cur = r & 1, nxt = cur ^ 1;
            if (r + 1 < RPB) {                    // issue next round's loads NOW
                const long long pb = bbase + (long long)(r + 1) * ROUND;
                #pragma unroll
                for (int j = 0; j < EPT / 4; ++j) {
                    long long e = pb + ((long long)j * TPB + t) * 4;
                    dr[nxt][j] = *reinterpret_cast<const int4*>(dst + e);
                    vr[nxt][j] = *reinterpret_cast<const float4*>(ea + e);
                }
            }
            h[t] = 0;
            __syncthreads();
            #pragma unroll
            for (int j = 0; j < EPT / 4; ++j) {
                atomicAdd(&h[dr[cur][j].x >> VSHIFT], 1);
                atomicAdd(&h[dr[cur][j].y >> VSHIFT], 1);
                atomicAdd(&h[dr[cur][j].z >> VSHIFT], 1);
                atomicAdd(&h[dr[cur][j].w >> VSHIFT], 1);
            }
            __syncthreads();
            int rt;
            int excl = block_excl_scan(h[t], t, wsum, &rt);
            pos[t] = excl;
            adj[t] = my_gbase - excl;
            __syncthreads();
            #pragma unroll
            for (int j = 0; j < EPT / 4; ++j) {
                int   dd[4] = {dr[cur][j].x, dr[cur][j].y, dr[cur][j].z, dr[cur][j].w};
                float vv[4] = {vr[cur][j].x, vr[cur][j].y, vr[cur][j].z, vr[cur][j].w};
                #pragma unroll
                for (int q = 0; q < 4; ++q) {
                    int b = dd[q] >> VSHIFT;
                    int slot = atomicAdd(&pos[b], 1);
                    stage[slot] = pack_pair(dd[q], vv[q]);
                }
            }
            __syncthreads();
            #pragma unroll
            for (int i0 = 0; i0 < ROUND; i0 += TPB) {   // rt == ROUND here
                int i = i0 + t;
                unsigned long long p = stage[i];
                int b = (int)((unsigned)(p & 0xffffffffull) >> VSHIFT);
                pairs[(size_t)(adj[b] + i)] = p;
            }
            my_gbase += h[t];
            // no trailing barrier: next round's post-reset barrier protects
            // stage (rewritten only after 3 barriers) and adj (after 2).
        }
    } else {
        // ---------- guarded tail path (last block only) ----------
        const long long bend = n_edge;
        for (int r = 0; r < RPB; ++r) {
            const long long rbase = bbase + (long long)r * ROUND;
            if (rbase >= bend) break;              // uniform across block
            h[t] = 0;
            __syncthreads();

            int4   dreg[EPT / 4];
            float4 vreg[EPT / 4];
            int    nval[EPT / 4];
            #pragma unroll
            for (int j = 0; j < EPT / 4; ++j) {
                long long e = rbase + ((long long)j * TPB + t) * 4;
                if (e + 4 <= bend) {
                    dreg[j] = *reinterpret_cast<const int4*>(dst + e);
                    vreg[j] = *reinterpret_cast<const float4*>(ea + e);
                    nval[j] = 4;
                } else {
                    int dd[4] = {0, 0, 0, 0};
                    float vv[4] = {0.f, 0.f, 0.f, 0.f};
                    int nv = 0;
                    for (int q = 0; q < 4; ++q) {
                        long long ee = e + q;
                        if (ee < bend) { dd[q] = dst[ee]; vv[q] = ea[ee]; nv = q + 1; }
                    }
                    dreg[j] = make_int4(dd[0], dd[1], dd[2], dd[3]);
                    vreg[j] = make_float4(vv[0], vv[1], vv[2], vv[3]);
                    nval[j] = nv;
                }
                if (nval[j] > 0) atomicAdd(&h[dreg[j].x >> VSHIFT], 1);
                if (nval[j] > 1) atomicAdd(&h[dreg[j].y >> VSHIFT], 1);
                if (nval[j] > 2) atomicAdd(&h[dreg[j].z >> VSHIFT], 1);
                if (nval[j] > 3) atomicAdd(&h[dreg[j].w >> VSHIFT], 1);
            }
            __syncthreads();

            int rt;
            int excl = block_excl_scan(h[t], t, wsum, &rt);
            pos[t] = excl;
            adj[t] = my_gbase - excl;
            __syncthreads();

            #pragma unroll
            for (int j = 0; j < EPT / 4; ++j) {
                int   dd[4] = {dreg[j].x, dreg[j].y, dreg[j].z, dreg[j].w};
                float vv[4] = {vreg[j].x, vreg[j].y, vreg[j].z, vreg[j].w};
                #pragma unroll
                for (int q = 0; q < 4; ++q) {
                    if (q < nval[j]) {
                        int b = dd[q] >> VSHIFT;
                        int slot = atomicAdd(&pos[b], 1);
                        stage[slot] = pack_pair(dd[q], vv[q]);
                    }
                }
            }
            __syncthreads();

            for (int i = t; i < rt; i += TPB) {
                unsigned long long p = stage[i];
                int b = (int)((unsigned)(p & 0xffffffffull) >> VSHIFT);
                pairs[(size_t)(adj[b] + i)] = p;
            }
            __syncthreads();
            my_gbase += h[t];
        }
    }
}

// SPLIT blocks per bucket: each accumulates its slice of the bucket's pairs
// into LDS (vectorized, unrolled loads for MLP), writes a partial slab.
__global__ __launch_bounds__(ATPB)
void accum_partial_kernel(const unsigned long long* __restrict__ pairs,
                          const int* __restrict__ base,
                          float* __restrict__ partials, int n_vert, int nb) {
    __shared__ __align__(16) float acc[VBUCK];
    const int b  = blockIdx.x % nb;
    const int sp = blockIdx.x / nb;
    const int t  = threadIdx.x;
    #pragma unroll
    for (int i = t; i < VBUCK; i += ATPB) acc[i] = 0.f;
    __syncthreads();

    const int s = base[b];
    const int e = base[b + 1];
    const long long len = e - s;
    const int i0 = s + (int)((len * sp) / SPLIT);
    const int i1 = s + (int)((len * (sp + 1)) / SPLIT);
    const int a0 = (i0 + 1) & ~1;          // first even index >= i0
    const int a1 = i1 & ~1;                // last even boundary <= i1

    // odd head / odd tail (at most one pair each)
    if (t == 0 && (i0 & 1) && i0 < i1) {
        unsigned long long p = pairs[i0];
        atomicAdd(&acc[(int)(p & (VBUCK - 1))],
                  __uint_as_float((unsigned)(p >> 32)));
    }
    if (t == 1 && (i1 & 1) && (i1 - 1) >= i0) {
        unsigned long long p = pairs[i1 - 1];
        atomicAdd(&acc[(int)(p & (VBUCK - 1))],
                  __uint_as_float((unsigned)(p >> 32)));
    }

    const int n2 = (a1 - a0) >> 1;         // ulonglong2 elements
    const ulonglong2* pv = reinterpret_cast<const ulonglong2*>(pairs + a0);
    int j = t;
    for (; j + 3 * ATPB < n2; j += 4 * ATPB) {
        ulonglong2 q0 = pv[j];
        ulonglong2 q1 = pv[j + ATPB];
        ulonglong2 q2 = pv[j + 2 * ATPB];
        ulonglong2 q3 = pv[j + 3 * ATPB];
        atomicAdd(&acc[(int)(q0.x & (VBUCK - 1))], __uint_as_float((unsigned)(q0.x >> 32)));
        atomicAdd(&acc[(int)(q0.y & (VBUCK - 1))], __uint_as_float((unsigned)(q0.y >> 32)));
        atomicAdd(&acc[(int)(q1.x & (VBUCK - 1))], __uint_as_float((unsigned)(q1.x >> 32)));
        atomicAdd(&acc[(int)(q1.y & (VBUCK - 1))], __uint_as_float((unsigned)(q1.y >> 32)));
        atomicAdd(&acc[(int)(q2.x & (VBUCK - 1))], __uint_as_float((unsigned)(q2.x >> 32)));
        atomicAdd(&acc[(int)(q2.y & (VBUCK - 1))], __uint_as_float((unsigned)(q2.y >> 32)));
        atomicAdd(&acc[(int)(q3.x & (VBUCK - 1))], __uint_as_float((unsigned)(q3.x >> 32)));
        atomicAdd(&acc[(int)(q3.y & (VBUCK - 1))], __uint_as_float((unsigned)(q3.y >> 32)));
    }
    for (; j < n2; j += ATPB) {
        ulonglong2 q = pv[j];
        atomicAdd(&acc[(int)(q.x & (VBUCK - 1))], __uint_as_float((unsigned)(q.x >> 32)));
        atomicAdd(&acc[(int)(q.y & (VBUCK - 1))], __uint_as_float((unsigned)(q.y >> 32)));
    }
    __syncthreads();

    float* pp = partials + (size_t)sp * n_vert;
    const int vbase = b << VSHIFT;
    if (vbase + VBUCK <= n_vert) {
        reinterpret_cast<float4*>(pp + vbase)[t] =
            reinterpret_cast<const float4*>(acc)[t];
    } else {
        for (int v = t; vbase + v < n_vert; v += ATPB) pp[vbase + v] = acc[v];
    }
}

// Sum SPLIT partials + vertex update; 4 vertices/thread, float4 I/O.
__global__ void final_update_kernel(const float* __restrict__ partials,
                                    const float* __restrict__ va,
                                    const float* __restrict__ g,
                                    float* __restrict__ out, int n_vert) {
    const int gt = blockIdx.x * blockDim.x + threadIdx.x;
    const float w = g[0];
    const int v0 = gt * 4;
    if (v0 + 4 <= n_vert) {
        float4 c = reinterpret_cast<const float4*>(partials)[gt];
        #pragma unroll
        for (int sp = 1; sp < SPLIT; ++sp) {
            float4 c2 = reinterpret_cast<const float4*>(
                            partials + (size_t)sp * n_vert)[gt];
            c.x += c2.x; c.y += c2.y; c.z += c2.z; c.w += c2.w;
        }
        float4 f0 = reinterpret_cast<const float4*>(va)[gt * 3 + 0];
        float4 f1 = reinterpret_cast<const float4*>(va)[gt * 3 + 1];
        float4 f2 = reinterpret_cast<const float4*>(va)[gt * 3 + 2];
        float4 o0, o1, o2;
        o0.x = f0.x; o0.y = f0.y; o0.z = f0.z + w * (f0.y - c.x) / f0.x;
        o0.w = f0.w; o1.x = f1.x; o1.y = f1.y + w * (f1.x - c.y) / f0.w;
        o1.z = f1.z; o1.w = f1.w; o2.x = f2.x + w * (f1.w - c.z) / f1.z;
        o2.y = f2.y; o2.z = f2.z; o2.w = f2.w + w * (f2.z - c.w) / f2.y;
        reinterpret_cast<float4*>(out)[gt * 3 + 0] = o0;
        reinterpret_cast<float4*>(out)[gt * 3 + 1] = o1;
        reinterpret_cast<float4*>(out)[gt * 3 + 2] = o2;
    } else {
        for (int i = v0; i < n_vert; ++i) {
            float c = 0.f;
            #pragma unroll
            for (int sp = 0; sp < SPLIT; ++sp)
                c += partials[(size_t)sp * n_vert + i];
            float A = va[3 * i], bb = va[3 * i + 1], x = va[3 * i + 2];
            out[3 * i]     = A;
            out[3 * i + 1] = bb;
            out[3 * i + 2] = x + w * (bb - c) / A;
        }
    }
}

// Round-9 fused path (used if partials don't fit in ws).
__global__ void accum_update_kernel(const unsigned long long* __restrict__ pairs,
                                    const int* __restrict__ base,
                                    const float* __restrict__ va,
                                    const float* __restrict__ g,
                                    float* __restrict__ out, int n_vert) {
    __shared__ __align__(16) float acc[VBUCK];
    const int b = blockIdx.x;
    const int T = blockDim.x;                  // 1024
    for (int t = threadIdx.x; t < VBUCK; t += T) acc[t] = 0.f;
    __syncthreads();
    const int s = base[b];
    const int e = base[b + 1];
    for (int i = s + threadIdx.x; i < e; i += T) {
        unsigned long long p = pairs[i];
        atomicAdd(&acc[(int)(p & (VBUCK - 1))],
                  __uint_as_float((unsigned)(p >> 32)));
    }
    __syncthreads();

    const float w = g[0];
    const int vbase = b << VSHIFT;
    const int t = threadIdx.x;
    const int v0 = vbase + t * 4;
    if (v0 + 4 <= n_vert) {
        const int gt = v0 >> 2;
        float4 f0 = reinterpret_cast<const float4*>(va)[gt * 3 + 0];
        float4 f1 = reinterpret_cast<const float4*>(va)[gt * 3 + 1];
        float4 f2 = reinterpret_cast<const float4*>(va)[gt * 3 + 2];
        float4 c  = reinterpret_cast<const float4*>(acc)[t];
        float4 o0, o1, o2;
        o0.x = f0.x; o0.y = f0.y; o0.z = f0.z + w * (f0.y - c.x) / f0.x;
        o0.w = f0.w; o1.x = f1.x; o1.y = f1.y + w * (f1.x - c.y) / f0.w;
        o1.z = f1.z; o1.w = f1.w; o2.x = f2.x + w * (f1.w - c.z) / f1.z;
        o2.y = f2.y; o2.z = f2.z; o2.w = f2.w + w * (f2.z - c.w) / f2.y;
        reinterpret_cast<float4*>(out)[gt * 3 + 0] = o0;
        reinterpret_cast<float4*>(out)[gt * 3 + 1] = o1;
        reinterpret_cast<float4*>(out)[gt * 3 + 2] = o2;
    } else {
        for (int i = v0; i < n_vert && i < v0 + 4; ++i) {
            float A = va[3 * i], bb = va[3 * i + 1], x = va[3 * i + 2];
            out[3 * i]     = A;
            out[3 * i + 1] = bb;
            out[3 * i + 2] = x + w * (bb - acc[i - vbase]) / A;
        }
    }
}

// ---- fallback path (insufficient scratch): device-scope atomics ----
__global__ void scatter_add_dev_kernel(const int* __restrict__ dst,
                                       const float* __restrict__ ea,
                                       float* __restrict__ acc, int n_edges4) {
    int i = blockIdx.x * blockDim.x + threadIdx.x;
    const int stride = gridDim.x * blockDim.x;
    for (; i < n_edges4; i += stride) {
        int4   d = reinterpret_cast<const int4*>(dst)[i];
        float4 v = reinterpret_cast<const float4*>(ea)[i];
        atomicAdd(&acc[d.x], v.x);
        atomicAdd(&acc[d.y], v.y);
        atomicAdd(&acc[d.z], v.z);
        atomicAdd(&acc[d.w], v.w);
    }
}

__global__ void update_kernel(const float* __restrict__ va,
                              const float* __restrict__ cbar,
                              const float* __restrict__ g,
                              float* __restrict__ out, int n) {
    int i = blockIdx.x * blockDim.x + threadIdx.x;
    if (i >= n) return;
    float A = va[3 * i], b = va[3 * i + 1], x = va[3 * i + 2];
    out[3 * i]     = A;
    out[3 * i + 1] = b;
    out[3 * i + 2] = x + g[0] * (b - cbar[i]) / A;
}

extern "C" void kernel_launch(void* const* d_in, const int* in_sizes, int n_in,
                              void* d_out, int out_size, void* d_ws, size_t ws_size,
                              hipStream_t stream) {
    const float* vertex_attr = (const float*)d_in[0];
    const int*   edgeij      = (const int*)d_in[1];   // row 0 = dst
    const float* edge_attr   = (const float*)d_in[2];
    const float* g           = (const float*)d_in[3];

    const int       n_vert = in_sizes[0] / 3;
    const long long n_edge = in_sizes[2];
    const int       nb     = (n_vert + VBUCK - 1) >> VSHIFT;
    const int       nblk   = (int)((n_edge + PBLK - 1) / PBLK);

    // ws layout: [histp][totals][base][pairs][partials (optional)]
    size_t histp_sz   = (size_t)NBMAX * nblk * sizeof(int);
    size_t totals_off = (histp_sz + 255) & ~(size_t)255;
    size_t base_off   = totals_off + NBMAX * sizeof(int);
    size_t pairs_off  = (base_off + (TPB + 1) * sizeof(int) + 255) & ~(size_t)255;
    size_t need1      = pairs_off + (size_t)n_edge * sizeof(unsigned long long);
    size_t part_off   = (need1 + 255) & ~(size_t)255;
    size_t need2      = part_off + (size_t)SPLIT * n_vert * sizeof(float);

    if (ws_size >= need1 && nb <= NBMAX) {
        int* histp  = (int*)d_ws;
        int* totals = (int*)((char*)d_ws + totals_off);
        int* basep  = (int*)((char*)d_ws + base_off);
        unsigned long long* pairs =
            (unsigned long long*)((char*)d_ws + pairs_off);

        hist_blocks_kernel<<<nblk, TPB, 0, stream>>>(edgeij, n_edge, nblk, histp);
        row_scan_kernel<<<nb, TPB, 0, stream>>>(histp, nblk, totals);
        base_scan_kernel<<<1, TPB, 0, stream>>>(totals, nb, basep);
        partition_kernel<<<nblk, TPB, 0, stream>>>(edgeij, edge_attr, n_edge,
                                                   nblk, histp, basep, pairs);
        if (ws_size >= need2) {
            float* partials = (float*)((char*)d_ws + part_off);
            accum_partial_kernel<<<nb * SPLIT, ATPB, 0, stream>>>(
                pairs, basep, partials, n_vert, nb);
            const int uthreads = (n_vert + 3) / 4;
            final_update_kernel<<<(uthreads + TPB - 1) / TPB, TPB, 0, stream>>>(
                partials, vertex_attr, g, (float*)d_out, n_vert);
        } else {
            accum_update_kernel<<<nb, 1024, 0, stream>>>(pairs, basep, vertex_attr,
                                                         g, (float*)d_out, n_vert);
        }
    } else {
        float* cbar = (float*)d_ws;
        hipMemsetAsync(cbar, 0, (size_t)n_vert * sizeof(float), stream);
        scatter_add_dev_kernel<<<4096, TPB, 0, stream>>>(edgeij, edge_attr, cbar,
                                                         (int)(n_edge / 4));
        update_kernel<<<(n_vert + TPB - 1) / TPB, TPB, 0, stream>>>(
            vertex_attr, cbar, g, (float*)d_out, n_vert);
    }
}